// Round 11
// baseline (337.109 us; speedup 1.0000x reference)
//
#include <hip/hip_runtime.h>
#include <cmath>

typedef _Float16 h8  __attribute__((ext_vector_type(8)));
typedef _Float16 h4v __attribute__((ext_vector_type(4)));
typedef float    f4  __attribute__((ext_vector_type(4)));

#define NB  4096
#define NIN 4096
#define NNP 512
#define NP1 4096
#define NP2 8192
#define NH  2048

__device__ __forceinline__ void g2l(const void* g, void* l) {
  __builtin_amdgcn_global_load_lds((const __attribute__((address_space(1))) void*)g,
                                   (__attribute__((address_space(3))) void*)l, 16, 0, 0);
}

// ---------------- pack f32 -> f16 (vectorized) ----------------
__global__ __launch_bounds__(256) void k_pack_f16(const float* __restrict__ in,
                                                  _Float16* __restrict__ out, int n4) {
  int i = blockIdx.x * 256 + threadIdx.x;
  if (i >= n4) return;
  f4 v = ((const f4*)in)[i];
  h4v o;
  o[0] = (_Float16)v[0]; o[1] = (_Float16)v[1];
  o[2] = (_Float16)v[2]; o[3] = (_Float16)v[3];
  ((h4v*)out)[i] = o;
}

// ---------------- transpose pack: out[n][k] = in[k][n] * optional mask ----------------
template<bool MASK>
__global__ __launch_bounds__(256) void k_packT(const float* __restrict__ in,
                                               const int* __restrict__ comp,
                                               _Float16* __restrict__ out, int K, int N) {
  __shared__ float tile[64][65];
  const int n0 = blockIdx.x * 64, k0 = blockIdx.y * 64;
  const int tx = threadIdx.x & 63, ty = threadIdx.x >> 6;
#pragma unroll
  for (int r = 0; r < 16; ++r) {
    int kk = r * 4 + ty;
    float v = in[(long)(k0 + kk) * N + n0 + tx];
    if (MASK) v *= (float)comp[(long)(k0 + kk) * NNP + ((n0 + tx) >> 3)];
    tile[kk][tx] = v;
  }
  __syncthreads();
#pragma unroll
  for (int r = 0; r < 16; ++r) {
    int nn = r * 4 + ty;
    out[(long)(n0 + nn) * K + k0 + tx] = (_Float16)tile[tx][nn];
  }
}

// ---------------- 256x256 fp16 GEMM, 16x16x32 frags, read-ahead pipelined 8-phase ----------------
// C = A[M,K] * BT[N,K]^T. EPI=0: C = acc + bias (fp16). EPI=1: fp16 split-K partial at ks*M*N.
// 8 waves (2m x 4n). A row = mh*128 + wm*64 + m*16 + lh ; B row = nh*128 + wn*32 + n*16 + lh.
// LDS 128KB: 2buf x {A half0,half1 ; B half0,half1}, each half [128 rows][128B] fp16.
// Zero-conflict read col (verified R6): (kq*64 + ls*16) ^ ((lh&7)<<4); staging = linear LDS
// dest + pre-swizzled global source.
// Pipelining: each phase's ds_reads load the NEXT phase's fragments into alternate register
// sets (afA/afB, bfA/bfB; B parity swaps per tile) -> MFMA never waits on LDS latency.
// Stages for tile t+2 spread P1..P4 of tile t; one vmcnt(6) per K-tile (ledger: 14 out, retires
// exactly the next tile's 8 stages). Plain ds_reads: compiler emits counted lgkm waits.
template<int EPI>
__global__ __launch_bounds__(512, 1) void k_gemm8(
    const _Float16* __restrict__ A, const _Float16* __restrict__ BT,
    const float* __restrict__ bias, _Float16* __restrict__ C,
    int M, int N, int K, int nbn, int ksplit) {
  extern __shared__ char smem[];
  // bijective XCD swizzle
  const int nwg = gridDim.x;
  const int q = nwg >> 3, r = nwg & 7;
  const int xcd = blockIdx.x & 7, idx = blockIdx.x >> 3;
  const int wg = (xcd < r ? xcd * (q + 1) : r * (q + 1) + (xcd - r) * q) + idx;
  const int tpk = nwg / ksplit;
  const int ks = wg / tpk;
  const int rem = wg - ks * tpk;
  const int bm = rem / nbn, bn = rem % nbn;
  const long m0 = (long)bm << 8, n0 = (long)bn << 8;
  const int Ks = K / ksplit;
  const int NT = Ks >> 6;              // BK=64, NT even (K multiples of 128)

  const int tid = threadIdx.x;
  const int lane = tid & 63, w = tid >> 6;
  const int wm = w >> 2, wn = w & 3;
  const int lh = lane & 15, ls = lane >> 4;
  const int swz = (lh & 7) << 4;
  const int c0 = (ls * 16) ^ swz;
  const int c1 = (64 + ls * 16) ^ swz;
  const int arow = (wm * 64 + lh) * 128;           // + mh*16384 + m_*2048
  const int brow = 32768 + (wn * 32 + lh) * 128;   // + nh*16384 + n_*2048

  const long sKb = (long)K * 2;
  const int scb = (((tid & 7) ^ ((tid >> 3) & 7)) << 4);
  const char* Ag = (const char*)A + (m0 + (tid >> 3)) * sKb + (long)ks * Ks * 2 + scb;
  const char* Bg = (const char*)BT + (n0 + (tid >> 3)) * sKb + (long)ks * Ks * 2 + scb;
  const long h64 = 64 * sKb, h128 = 128 * sKb;
  const int lw = w << 10;

#define STAGE_A(buf, hh, kb) do { \
    const char* s_ = Ag + (hh) * h128 + (kb); \
    char* d_ = smem + (buf) * 65536 + (hh) * 16384 + lw; \
    g2l(s_, d_); g2l(s_ + h64, d_ + 8192); } while (0)
#define STAGE_B(buf, hh, kb) do { \
    const char* s_ = Bg + (hh) * h128 + (kb); \
    char* d_ = smem + (buf) * 65536 + 32768 + (hh) * 16384 + lw; \
    g2l(s_, d_); g2l(s_ + h64, d_ + 8192); } while (0)
#define READ_A(dst, buf, mh) do { \
    _Pragma("unroll") for (int m_ = 0; m_ < 4; ++m_) { \
      dst[m_][0] = *(const h8*)(smem + (buf) * 65536 + (mh) * 16384 + arow + m_ * 2048 + c0); \
      dst[m_][1] = *(const h8*)(smem + (buf) * 65536 + (mh) * 16384 + arow + m_ * 2048 + c1); } } while (0)
#define READ_B(dst, buf, nh) do { \
    _Pragma("unroll") for (int n_ = 0; n_ < 2; ++n_) { \
      dst[n_][0] = *(const h8*)(smem + (buf) * 65536 + (nh) * 16384 + brow + n_ * 2048 + c0); \
      dst[n_][1] = *(const h8*)(smem + (buf) * 65536 + (nh) * 16384 + brow + n_ * 2048 + c1); } } while (0)
#define MM(mh, nh, aset, bset) do { \
    _Pragma("unroll") for (int kq_ = 0; kq_ < 2; ++kq_) \
    _Pragma("unroll") for (int m_ = 0; m_ < 4; ++m_) \
    _Pragma("unroll") for (int n_ = 0; n_ < 2; ++n_) \
      acc[mh][nh][m_][n_] = __builtin_amdgcn_mfma_f32_16x16x32_f16(aset[m_][kq_], bset[n_][kq_], acc[mh][nh][m_][n_], 0, 0, 0); } while (0)
#define BAR() asm volatile("s_barrier" ::: "memory")
#define VM6() asm volatile("s_waitcnt vmcnt(6)" ::: "memory")
#define VM8() asm volatile("s_waitcnt vmcnt(8)" ::: "memory")
#define PR1() __builtin_amdgcn_s_setprio(1)
#define PR0() __builtin_amdgcn_s_setprio(0)

  f4 acc[2][2][4][2] = {};   // [mh][nh][m][n]
  h8 afA[4][2], afB[4][2];   // A half0 / half1 fragment sets
  h8 bfA[2][2], bfB[2][2];   // B sets: even tiles B0->bfA,B1->bfB; odd tiles swapped

  auto kc = [&](int t) -> long { return (long)(t < NT ? t : NT - 1) << 7; };

  // prologue: stage tile0->buf0 (8 g2l), tile1->buf1 (8 g2l); retire tile0; preload A0,B0(t0)
  STAGE_A(0, 0, kc(0)); STAGE_B(0, 0, kc(0)); STAGE_B(0, 1, kc(0)); STAGE_A(0, 1, kc(0));
  STAGE_A(1, 0, kc(1)); STAGE_B(1, 0, kc(1)); STAGE_B(1, 1, kc(1)); STAGE_A(1, 1, kc(1));
  VM8();
  BAR();
  READ_A(afA, 0, 0);
  READ_B(bfA, 0, 0);

  for (int t2 = 0; t2 < NT; t2 += 2) {
    // ================= even tile t2 (buf0) =================
    // P1: MFMA(A0,B0); read B1(t2) ahead; stage A0(t2+2)
    BAR();
    READ_B(bfB, 0, 1);
    STAGE_A(0, 0, kc(t2 + 2));
    PR1(); MM(0, 0, afA, bfA); PR0();
    // P2: MFMA(A0,B1); read A1(t2) ahead; stage B1(t2+2)
    BAR();
    READ_A(afB, 0, 1);
    STAGE_B(0, 1, kc(t2 + 2));
    PR1(); MM(0, 1, afA, bfB); PR0();
    // P3: MFMA(A1,B1); gate tile t2+1 (vmcnt ledger = 14 -> retire its 8); read A0(t2+1)
    BAR();
    STAGE_A(0, 1, kc(t2 + 2));
    VM6();
    READ_A(afA, 1, 0);
    PR1(); MM(1, 1, afB, bfB); PR0();
    // P4: MFMA(A1,B0); read B0(t2+1)->bfB (odd parity); stage B0(t2+2)
    BAR();
    READ_B(bfB, 1, 0);
    STAGE_B(0, 0, kc(t2 + 2));
    PR1(); MM(1, 0, afB, bfA); PR0();
    // ================= odd tile t2+1 (buf1) =================
    // P5: MFMA(A0,B0=bfB); read B1(t2+1)->bfA; stage A0(t2+3)
    BAR();
    READ_B(bfA, 1, 1);
    STAGE_A(1, 0, kc(t2 + 3));
    PR1(); MM(0, 0, afA, bfB); PR0();
    // P6: MFMA(A0,B1=bfA); read A1(t2+1); stage B1(t2+3)
    BAR();
    READ_A(afB, 1, 1);
    STAGE_B(1, 1, kc(t2 + 3));
    PR1(); MM(0, 1, afA, bfA); PR0();
    // P7: MFMA(A1,B1=bfA); gate tile t2+2 (retire P1..P4 stages); read A0(t2+2)
    BAR();
    STAGE_A(1, 1, kc(t2 + 3));
    VM6();
    READ_A(afA, 0, 0);
    PR1(); MM(1, 1, afB, bfA); PR0();
    // P8: MFMA(A1,B0=bfB); read B0(t2+2)->bfA (even parity); stage B0(t2+3)
    BAR();
    READ_B(bfA, 0, 0);
    STAGE_B(1, 0, kc(t2 + 3));
    PR1(); MM(1, 0, afB, bfB); PR0();
  }

  // epilogue: 16x16 C/D layout col=lane&15, row=(lane>>4)*4+j
  _Float16* dst = (EPI == 1) ? (C + (long)ks * M * N) : C;
#pragma unroll
  for (int mh = 0; mh < 2; ++mh)
#pragma unroll
  for (int m = 0; m < 4; ++m) {
    const long r0 = m0 + mh * 128 + wm * 64 + m * 16 + ls * 4;
#pragma unroll
    for (int nh = 0; nh < 2; ++nh)
#pragma unroll
    for (int n = 0; n < 2; ++n) {
      const long c = n0 + nh * 128 + wn * 32 + n * 16 + lh;
      const float bv = (EPI == 0) ? bias[c] : 0.f;
#pragma unroll
      for (int j = 0; j < 4; ++j)
        dst[(r0 + j) * N + c] = (_Float16)(acc[mh][nh][m][n][j] + bv);
    }
  }
#undef STAGE_A
#undef STAGE_B
#undef READ_A
#undef READ_B
#undef MM
#undef BAR
#undef VM6
#undef VM8
#undef PR1
#undef PR0
}

// ---------------- block-diagonal GEMM2 ----------------
__global__ __launch_bounds__(256) void k_gemm2(const _Float16* __restrict__ out1,
                                               const float* __restrict__ fc2w,
                                               const float* __restrict__ fc2b,
                                               _Float16* __restrict__ out2) {
  const int b0 = (blockIdx.x >> 4) * 64;
  const int p  = (blockIdx.x & 15) * 32 + (threadIdx.x & 31);
  const int bsub = threadIdx.x >> 5;
  f4 bb0 = *(const f4*)&fc2b[p * 16 + 0];
  f4 bb1 = *(const f4*)&fc2b[p * 16 + 4];
  f4 bb2 = *(const f4*)&fc2b[p * 16 + 8];
  f4 bb3 = *(const f4*)&fc2b[p * 16 + 12];
  for (int r = 0; r < 8; ++r) {
    const int b = b0 + r * 8 + bsub;
    h8 qv = *(const h8*)&out1[(long)b * NP1 + p * 8];
    f4 a0 = bb0, a1 = bb1, a2 = bb2, a3 = bb3;
#pragma unroll
    for (int i = 0; i < 8; ++i) {
      const float qi = (float)qv[i];
      const f4* wr = (const f4*)&fc2w[(long)(p * 8 + i) * NP2 + p * 16];
      a0 += qi * wr[0]; a1 += qi * wr[1]; a2 += qi * wr[2]; a3 += qi * wr[3];
    }
    h8 o0, o1;
#pragma unroll
    for (int u = 0; u < 4; ++u) {
      o0[u] = (_Float16)a0[u]; o0[4 + u] = (_Float16)a1[u];
      o1[u] = (_Float16)a2[u]; o1[4 + u] = (_Float16)a3[u];
    }
    h8* dstp = (h8*)&out2[(long)b * NP2 + p * 16];
    dstp[0] = o0; dstp[1] = o1;
  }
}

// ---------------- fused splitK-reduce + bias + relu + GEMM4 + sigmoid ----------------
__global__ __launch_bounds__(256) void k_logits(const _Float16* __restrict__ part,
                                                const float* __restrict__ b1,
                                                const float* __restrict__ w2,
                                                const float* __restrict__ b2,
                                                float* __restrict__ logits,
                                                float* __restrict__ hazards) {
  const int lane = threadIdx.x & 63;
  const int b = blockIdx.x * 4 + (threadIdx.x >> 6);
  const long off2 = (long)NB * NH;
  f4 acc = {0.f, 0.f, 0.f, 0.f};
  const _Float16* p0 = part + (long)b * NH;
  const _Float16* p1 = p0 + off2;
#pragma unroll
  for (int c4 = 0; c4 < 4; ++c4) {
    const int k0 = c4 * 512 + lane * 8;
    h8 a = *(const h8*)&p0[k0];
    h8 bb = *(const h8*)&p1[k0];
    f4 bva = *(const f4*)&b1[k0];
    f4 bvb = *(const f4*)&b1[k0 + 4];
#pragma unroll
    for (int u = 0; u < 8; ++u) {
      const float bias = (u < 4) ? bva[u] : bvb[u - 4];
      const float hv = fmaxf((float)a[u] + (float)bb[u] + bias, 0.f);
      acc += hv * *(const f4*)&w2[(long)(k0 + u) * 4];
    }
  }
#pragma unroll
  for (int off = 32; off > 0; off >>= 1) {
#pragma unroll
    for (int u = 0; u < 4; ++u) acc[u] += __shfl_xor(acc[u], off, 64);
  }
  if (lane == 0) {
    f4 lg = acc + *(const f4*)b2;
    ((f4*)logits)[b] = lg;
    f4 hz;
#pragma unroll
    for (int u = 0; u < 4; ++u) hz[u] = 1.f / (1.f + expf(-lg[u]));
    ((f4*)hazards)[b] = hz;
  }
}

// ---------------- cumprod along batch + first-occurrence argmax ----------------
__global__ __launch_bounds__(256) void k_final(const float* __restrict__ logits,
                                               const float* __restrict__ hazards,
                                               float* __restrict__ S,
                                               float* __restrict__ yhat) {
  const int c = blockIdx.x;
  const int t = threadIdx.x;
  __shared__ float pl[256];
  __shared__ float mv[256];
  __shared__ int   mi[256];
  float prod = 1.f;
  float best = -1e30f; int bi = 0;
  for (int i = 0; i < 16; ++i) {
    const int b = t * 16 + i;
    prod *= (1.f - hazards[b * 4 + c]);
    const float lg = logits[b * 4 + c];
    if (lg > best) { best = lg; bi = b; }
  }
  pl[t] = prod; mv[t] = best; mi[t] = bi;
  __syncthreads();
  for (int off = 1; off < 256; off <<= 1) {
    float cur  = pl[t];
    float prev = (t >= off) ? pl[t - off] : 1.f;
    __syncthreads();
    pl[t] = cur * prev;
    __syncthreads();
  }
  float s = (t == 0) ? 1.f : pl[t - 1];
  for (int i = 0; i < 16; ++i) {
    const int b = t * 16 + i;
    s *= (1.f - hazards[b * 4 + c]);
    S[b * 4 + c] = s;
  }
  for (int off = 128; off > 0; off >>= 1) {
    if (t < off) {
      float ov = mv[t + off]; int oi = mi[t + off];
      if (ov > mv[t] || (ov == mv[t] && oi < mi[t])) { mv[t] = ov; mi[t] = oi; }
    }
    __syncthreads();
  }
  if (t == 0) yhat[c] = (float)mi[0];
}

extern "C" void kernel_launch(void* const* d_in, const int* in_sizes, int n_in,
                              void* d_out, int out_size, void* d_ws, size_t ws_size,
                              hipStream_t stream) {
  (void)in_sizes; (void)n_in; (void)out_size; (void)ws_size;
  const float* x    = (const float*)d_in[0];
  const float* fc1w = (const float*)d_in[1];
  const float* fc1b = (const float*)d_in[2];
  const float* fc2w = (const float*)d_in[3];
  const float* fc2b = (const float*)d_in[4];
  const float* w1   = (const float*)d_in[5];
  const float* b1   = (const float*)d_in[6];
  const float* w2   = (const float*)d_in[7];
  const float* b2   = (const float*)d_in[8];
  const int*   comp = (const int*)d_in[9];

  char* ws = (char*)d_ws;
  const size_t MB = 1024ull * 1024ull;
  // region plan (peak 160MB):
  //   [0,32M)    xh     -> dead after GEMM1 -> w1Th
  //   [32M,64M)  w1mT   -> dead after GEMM1 -> part (fp16 2x16MB)
  //   [64M,96M)  out1h  -> dead after GEMM2 -> logits
  //   [96M,160M) out2h
  _Float16* xh     = (_Float16*)(ws + 0);
  _Float16* w1mT   = (_Float16*)(ws + 32 * MB);
  _Float16* out1h  = (_Float16*)(ws + 64 * MB);
  _Float16* out2h  = (_Float16*)(ws + 96 * MB);
  _Float16* w1Th   = (_Float16*)(ws + 0);
  _Float16* part   = (_Float16*)(ws + 32 * MB);
  float*    logits = (float*)(ws + 64 * MB);
  float*    outF   = (float*)d_out;

  hipFuncSetAttribute(reinterpret_cast<const void*>(k_gemm8<0>),
                      hipFuncAttributeMaxDynamicSharedMemorySize, 131072);
  hipFuncSetAttribute(reinterpret_cast<const void*>(k_gemm8<1>),
                      hipFuncAttributeMaxDynamicSharedMemorySize, 131072);

  // 1) pack x -> fp16
  k_pack_f16<<<(NB * NIN / 4) / 256, 256, 0, stream>>>(x, xh, NB * NIN / 4);
  // 2) pack (fc1_w * mask1)^T -> fp16 [P1][IN]
  k_packT<true><<<dim3(NP1 / 64, NIN / 64), 256, 0, stream>>>(fc1w, comp, w1mT, NIN, NP1);
  // 3) GEMM1: out1 = x @ fc1w_masked + fc1_b
  k_gemm8<0><<<(NB / 256) * (NP1 / 256), 512, 131072, stream>>>(
      xh, w1mT, fc1b, out1h, NB, NP1, NIN, NP1 / 256, 1);
  // 4) block-diagonal GEMM2 -> out2 fp16
  k_gemm2<<<(NB / 64) * (NNP / 32), 256, 0, stream>>>(out1h, fc2w, fc2b, out2h);
  // 5) pack w1^T -> fp16 [H][P2] (overlays dead xh)
  k_packT<false><<<dim3(NH / 64, NP2 / 64), 256, 0, stream>>>(w1, nullptr, w1Th, NP2, NH);
  // 6) GEMM3 split-K=2: fp16 partials = out2 @ w1 (overlays dead w1mT)
  k_gemm8<1><<<(NB / 256) * (NH / 256) * 2, 512, 131072, stream>>>(
      out2h, w1Th, nullptr, part, NB, NH, NP2, NH / 256, 2);
  // 7) fused: h = relu(p0+p1+b1); logits = h@w2+b2; hazards = sigmoid
  k_logits<<<NB / 4, 256, 0, stream>>>(part, b1, w2, b2, logits, outF);
  // 8) S and Y_hat
  k_final<<<4, 256, 0, stream>>>(logits, outF, outF + NB * 4, outF + 2 * NB * 4);
}

// Round 12
// 336.812 us; speedup vs baseline: 1.0009x; 1.0009x over previous
//
#include <hip/hip_runtime.h>
#include <cmath>

typedef _Float16 h8  __attribute__((ext_vector_type(8)));
typedef _Float16 h4v __attribute__((ext_vector_type(4)));
typedef float    f4  __attribute__((ext_vector_type(4)));

#define NB  4096
#define NIN 4096
#define NNP 512
#define NP1 4096
#define NP2 8192
#define NH  2048

__device__ __forceinline__ void g2l(const void* g, void* l) {
  __builtin_amdgcn_global_load_lds((const __attribute__((address_space(1))) void*)g,
                                   (__attribute__((address_space(3))) void*)l, 16, 0, 0);
}

// ---------------- pack f32 -> f16 (vectorized) ----------------
__global__ __launch_bounds__(256) void k_pack_f16(const float* __restrict__ in,
                                                  _Float16* __restrict__ out, int n4) {
  int i = blockIdx.x * 256 + threadIdx.x;
  if (i >= n4) return;
  f4 v = ((const f4*)in)[i];
  h4v o;
  o[0] = (_Float16)v[0]; o[1] = (_Float16)v[1];
  o[2] = (_Float16)v[2]; o[3] = (_Float16)v[3];
  ((h4v*)out)[i] = o;
}

// ---------------- transpose pack: out[n][k] = in[k][n] * optional mask ----------------
template<bool MASK>
__global__ __launch_bounds__(256) void k_packT(const float* __restrict__ in,
                                               const int* __restrict__ comp,
                                               _Float16* __restrict__ out, int K, int N) {
  __shared__ float tile[64][65];
  const int n0 = blockIdx.x * 64, k0 = blockIdx.y * 64;
  const int tx = threadIdx.x & 63, ty = threadIdx.x >> 6;
#pragma unroll
  for (int r = 0; r < 16; ++r) {
    int kk = r * 4 + ty;
    float v = in[(long)(k0 + kk) * N + n0 + tx];
    if (MASK) v *= (float)comp[(long)(k0 + kk) * NNP + ((n0 + tx) >> 3)];
    tile[kk][tx] = v;
  }
  __syncthreads();
#pragma unroll
  for (int r = 0; r < 16; ++r) {
    int nn = r * 4 + ty;
    out[(long)(n0 + nn) * K + k0 + tx] = (_Float16)tile[tx][nn];
  }
}

// ---------------- 256x256 fp16 GEMM, 16x16x32 frags, read-ahead pipelined 8-phase ----------------
// C = A[M,K] * BT[N,K]^T. EPI=0: C = acc + bias (fp16). EPI=1: fp16 split-K partial at ks*M*N.
// 8 waves (2m x 4n). A row = mh*128 + wm*64 + m*16 + lh ; B row = nh*128 + wn*32 + n*16 + lh.
// LDS 128KB: 2buf x {A half0,half1 ; B half0,half1}, each half [128 rows][128B] fp16.
// Zero-conflict read col (verified R6): (kq*64 + ls*16) ^ ((lh&7)<<4); staging = linear LDS
// dest + pre-swizzled global source.
// Pipelining: each phase's ds_reads load the NEXT phase's fragments into alternate register
// sets (afA/afB, bfA/bfB; B parity swaps per tile) -> MFMA never waits on LDS latency.
// Stages for tile t+2 spread P1..P4 of tile t; one vmcnt(6) per K-tile (ledger: 14 out, retires
// exactly the next tile's 8 stages). Plain ds_reads: compiler emits counted lgkm waits.
template<int EPI>
__global__ __launch_bounds__(512, 1) void k_gemm8(
    const _Float16* __restrict__ A, const _Float16* __restrict__ BT,
    const float* __restrict__ bias, _Float16* __restrict__ C,
    int M, int N, int K, int nbn, int ksplit) {
  extern __shared__ char smem[];
  // bijective XCD swizzle
  const int nwg = gridDim.x;
  const int q = nwg >> 3, r = nwg & 7;
  const int xcd = blockIdx.x & 7, idx = blockIdx.x >> 3;
  const int wg = (xcd < r ? xcd * (q + 1) : r * (q + 1) + (xcd - r) * q) + idx;
  const int tpk = nwg / ksplit;
  const int ks = wg / tpk;
  const int rem = wg - ks * tpk;
  const int bm = rem / nbn, bn = rem % nbn;
  const long m0 = (long)bm << 8, n0 = (long)bn << 8;
  const int Ks = K / ksplit;
  const int NT = Ks >> 6;              // BK=64, NT even (K multiples of 128)

  const int tid = threadIdx.x;
  const int lane = tid & 63, w = tid >> 6;
  const int wm = w >> 2, wn = w & 3;
  const int lh = lane & 15, ls = lane >> 4;
  const int swz = (lh & 7) << 4;
  const int c0 = (ls * 16) ^ swz;
  const int c1 = (64 + ls * 16) ^ swz;
  const int arow = (wm * 64 + lh) * 128;           // + mh*16384 + m_*2048
  const int brow = 32768 + (wn * 32 + lh) * 128;   // + nh*16384 + n_*2048

  const long sKb = (long)K * 2;
  const int scb = (((tid & 7) ^ ((tid >> 3) & 7)) << 4);
  const char* Ag = (const char*)A + (m0 + (tid >> 3)) * sKb + (long)ks * Ks * 2 + scb;
  const char* Bg = (const char*)BT + (n0 + (tid >> 3)) * sKb + (long)ks * Ks * 2 + scb;
  const long h64 = 64 * sKb, h128 = 128 * sKb;
  const int lw = w << 10;

#define STAGE_A(buf, hh, kb) do { \
    const char* s_ = Ag + (hh) * h128 + (kb); \
    char* d_ = smem + (buf) * 65536 + (hh) * 16384 + lw; \
    g2l(s_, d_); g2l(s_ + h64, d_ + 8192); } while (0)
#define STAGE_B(buf, hh, kb) do { \
    const char* s_ = Bg + (hh) * h128 + (kb); \
    char* d_ = smem + (buf) * 65536 + 32768 + (hh) * 16384 + lw; \
    g2l(s_, d_); g2l(s_ + h64, d_ + 8192); } while (0)
#define READ_A(dst, buf, mh) do { \
    _Pragma("unroll") for (int m_ = 0; m_ < 4; ++m_) { \
      dst[m_][0] = *(const h8*)(smem + (buf) * 65536 + (mh) * 16384 + arow + m_ * 2048 + c0); \
      dst[m_][1] = *(const h8*)(smem + (buf) * 65536 + (mh) * 16384 + arow + m_ * 2048 + c1); } } while (0)
#define READ_B(dst, buf, nh) do { \
    _Pragma("unroll") for (int n_ = 0; n_ < 2; ++n_) { \
      dst[n_][0] = *(const h8*)(smem + (buf) * 65536 + (nh) * 16384 + brow + n_ * 2048 + c0); \
      dst[n_][1] = *(const h8*)(smem + (buf) * 65536 + (nh) * 16384 + brow + n_ * 2048 + c1); } } while (0)
#define MM(mh, nh, aset, bset) do { \
    _Pragma("unroll") for (int kq_ = 0; kq_ < 2; ++kq_) \
    _Pragma("unroll") for (int m_ = 0; m_ < 4; ++m_) \
    _Pragma("unroll") for (int n_ = 0; n_ < 2; ++n_) \
      acc[mh][nh][m_][n_] = __builtin_amdgcn_mfma_f32_16x16x32_f16(aset[m_][kq_], bset[n_][kq_], acc[mh][nh][m_][n_], 0, 0, 0); } while (0)
#define BAR() asm volatile("s_barrier" ::: "memory")
#define VM6() asm volatile("s_waitcnt vmcnt(6)" ::: "memory")
#define VM8() asm volatile("s_waitcnt vmcnt(8)" ::: "memory")
#define PR1() __builtin_amdgcn_s_setprio(1)
#define PR0() __builtin_amdgcn_s_setprio(0)

  f4 acc[2][2][4][2] = {};   // [mh][nh][m][n]
  h8 afA[4][2], afB[4][2];   // A half0 / half1 fragment sets
  h8 bfA[2][2], bfB[2][2];   // B sets: even tiles B0->bfA,B1->bfB; odd tiles swapped

  auto kc = [&](int t) -> long { return (long)(t < NT ? t : NT - 1) << 7; };

  // prologue: stage tile0->buf0 (8 g2l), tile1->buf1 (8 g2l); retire tile0; preload A0,B0(t0)
  STAGE_A(0, 0, kc(0)); STAGE_B(0, 0, kc(0)); STAGE_B(0, 1, kc(0)); STAGE_A(0, 1, kc(0));
  STAGE_A(1, 0, kc(1)); STAGE_B(1, 0, kc(1)); STAGE_B(1, 1, kc(1)); STAGE_A(1, 1, kc(1));
  VM8();
  BAR();
  READ_A(afA, 0, 0);
  READ_B(bfA, 0, 0);

  for (int t2 = 0; t2 < NT; t2 += 2) {
    // ================= even tile t2 (buf0) =================
    // P1: MFMA(A0,B0); read B1(t2) ahead; stage A0(t2+2)
    BAR();
    READ_B(bfB, 0, 1);
    STAGE_A(0, 0, kc(t2 + 2));
    PR1(); MM(0, 0, afA, bfA); PR0();
    // P2: MFMA(A0,B1); read A1(t2) ahead; stage B1(t2+2)
    BAR();
    READ_A(afB, 0, 1);
    STAGE_B(0, 1, kc(t2 + 2));
    PR1(); MM(0, 1, afA, bfB); PR0();
    // P3: MFMA(A1,B1); gate tile t2+1 (vmcnt ledger = 14 -> retire its 8); read A0(t2+1)
    BAR();
    STAGE_A(0, 1, kc(t2 + 2));
    VM6();
    READ_A(afA, 1, 0);
    PR1(); MM(1, 1, afB, bfB); PR0();
    // P4: MFMA(A1,B0); read B0(t2+1)->bfB (odd parity); stage B0(t2+2)
    BAR();
    READ_B(bfB, 1, 0);
    STAGE_B(0, 0, kc(t2 + 2));
    PR1(); MM(1, 0, afB, bfA); PR0();
    // ================= odd tile t2+1 (buf1) =================
    // P5: MFMA(A0,B0=bfB); read B1(t2+1)->bfA; stage A0(t2+3)
    BAR();
    READ_B(bfA, 1, 1);
    STAGE_A(1, 0, kc(t2 + 3));
    PR1(); MM(0, 0, afA, bfB); PR0();
    // P6: MFMA(A0,B1=bfA); read A1(t2+1); stage B1(t2+3)
    BAR();
    READ_A(afB, 1, 1);
    STAGE_B(1, 1, kc(t2 + 3));
    PR1(); MM(0, 1, afA, bfA); PR0();
    // P7: MFMA(A1,B1=bfA); gate tile t2+2 (retire P1..P4 stages); read A0(t2+2)
    BAR();
    STAGE_A(1, 1, kc(t2 + 3));
    VM6();
    READ_A(afA, 0, 0);
    PR1(); MM(1, 1, afB, bfA); PR0();
    // P8: MFMA(A1,B0=bfB); read B0(t2+2)->bfA (even parity); stage B0(t2+3)
    BAR();
    READ_B(bfA, 0, 0);
    STAGE_B(1, 0, kc(t2 + 3));
    PR1(); MM(1, 0, afB, bfB); PR0();
  }

  // epilogue: 16x16 C/D layout col=lane&15, row=(lane>>4)*4+j
  _Float16* dst = (EPI == 1) ? (C + (long)ks * M * N) : C;
#pragma unroll
  for (int mh = 0; mh < 2; ++mh)
#pragma unroll
  for (int m = 0; m < 4; ++m) {
    const long r0 = m0 + mh * 128 + wm * 64 + m * 16 + ls * 4;
#pragma unroll
    for (int nh = 0; nh < 2; ++nh)
#pragma unroll
    for (int n = 0; n < 2; ++n) {
      const long c = n0 + nh * 128 + wn * 32 + n * 16 + lh;
      const float bv = (EPI == 0) ? bias[c] : 0.f;
#pragma unroll
      for (int j = 0; j < 4; ++j)
        dst[(r0 + j) * N + c] = (_Float16)(acc[mh][nh][m][n][j] + bv);
    }
  }
#undef STAGE_A
#undef STAGE_B
#undef READ_A
#undef READ_B
#undef MM
#undef BAR
#undef VM6
#undef VM8
#undef PR1
#undef PR0
}

// ---------------- block-diagonal GEMM2 ----------------
__global__ __launch_bounds__(256) void k_gemm2(const _Float16* __restrict__ out1,
                                               const float* __restrict__ fc2w,
                                               const float* __restrict__ fc2b,
                                               _Float16* __restrict__ out2) {
  const int b0 = (blockIdx.x >> 4) * 64;
  const int p  = (blockIdx.x & 15) * 32 + (threadIdx.x & 31);
  const int bsub = threadIdx.x >> 5;
  f4 bb0 = *(const f4*)&fc2b[p * 16 + 0];
  f4 bb1 = *(const f4*)&fc2b[p * 16 + 4];
  f4 bb2 = *(const f4*)&fc2b[p * 16 + 8];
  f4 bb3 = *(const f4*)&fc2b[p * 16 + 12];
  for (int r = 0; r < 8; ++r) {
    const int b = b0 + r * 8 + bsub;
    h8 qv = *(const h8*)&out1[(long)b * NP1 + p * 8];
    f4 a0 = bb0, a1 = bb1, a2 = bb2, a3 = bb3;
#pragma unroll
    for (int i = 0; i < 8; ++i) {
      const float qi = (float)qv[i];
      const f4* wr = (const f4*)&fc2w[(long)(p * 8 + i) * NP2 + p * 16];
      a0 += qi * wr[0]; a1 += qi * wr[1]; a2 += qi * wr[2]; a3 += qi * wr[3];
    }
    h8 o0, o1;
#pragma unroll
    for (int u = 0; u < 4; ++u) {
      o0[u] = (_Float16)a0[u]; o0[4 + u] = (_Float16)a1[u];
      o1[u] = (_Float16)a2[u]; o1[4 + u] = (_Float16)a3[u];
    }
    h8* dstp = (h8*)&out2[(long)b * NP2 + p * 16];
    dstp[0] = o0; dstp[1] = o1;
  }
}

// ---------------- fused splitK-reduce + bias + relu + GEMM4 + sigmoid ----------------
__global__ __launch_bounds__(256) void k_logits(const _Float16* __restrict__ part,
                                                const float* __restrict__ b1,
                                                const float* __restrict__ w2,
                                                const float* __restrict__ b2,
                                                float* __restrict__ logits,
                                                float* __restrict__ hazards) {
  const int lane = threadIdx.x & 63;
  const int b = blockIdx.x * 4 + (threadIdx.x >> 6);
  const long off2 = (long)NB * NH;
  f4 acc = {0.f, 0.f, 0.f, 0.f};
  const _Float16* p0 = part + (long)b * NH;
  const _Float16* p1 = p0 + off2;
#pragma unroll
  for (int c4 = 0; c4 < 4; ++c4) {
    const int k0 = c4 * 512 + lane * 8;
    h8 a = *(const h8*)&p0[k0];
    h8 bb = *(const h8*)&p1[k0];
    f4 bva = *(const f4*)&b1[k0];
    f4 bvb = *(const f4*)&b1[k0 + 4];
#pragma unroll
    for (int u = 0; u < 8; ++u) {
      const float bias = (u < 4) ? bva[u] : bvb[u - 4];
      const float hv = fmaxf((float)a[u] + (float)bb[u] + bias, 0.f);
      acc += hv * *(const f4*)&w2[(long)(k0 + u) * 4];
    }
  }
#pragma unroll
  for (int off = 32; off > 0; off >>= 1) {
#pragma unroll
    for (int u = 0; u < 4; ++u) acc[u] += __shfl_xor(acc[u], off, 64);
  }
  if (lane == 0) {
    f4 lg = acc + *(const f4*)b2;
    ((f4*)logits)[b] = lg;
    f4 hz;
#pragma unroll
    for (int u = 0; u < 4; ++u) hz[u] = 1.f / (1.f + expf(-lg[u]));
    ((f4*)hazards)[b] = hz;
  }
}

// ---------------- cumprod along batch + first-occurrence argmax ----------------
__global__ __launch_bounds__(256) void k_final(const float* __restrict__ logits,
                                               const float* __restrict__ hazards,
                                               float* __restrict__ S,
                                               float* __restrict__ yhat) {
  const int c = blockIdx.x;
  const int t = threadIdx.x;
  __shared__ float pl[256];
  __shared__ float mv[256];
  __shared__ int   mi[256];
  float prod = 1.f;
  float best = -1e30f; int bi = 0;
  for (int i = 0; i < 16; ++i) {
    const int b = t * 16 + i;
    prod *= (1.f - hazards[b * 4 + c]);
    const float lg = logits[b * 4 + c];
    if (lg > best) { best = lg; bi = b; }
  }
  pl[t] = prod; mv[t] = best; mi[t] = bi;
  __syncthreads();
  for (int off = 1; off < 256; off <<= 1) {
    float cur  = pl[t];
    float prev = (t >= off) ? pl[t - off] : 1.f;
    __syncthreads();
    pl[t] = cur * prev;
    __syncthreads();
  }
  float s = (t == 0) ? 1.f : pl[t - 1];
  for (int i = 0; i < 16; ++i) {
    const int b = t * 16 + i;
    s *= (1.f - hazards[b * 4 + c]);
    S[b * 4 + c] = s;
  }
  for (int off = 128; off > 0; off >>= 1) {
    if (t < off) {
      float ov = mv[t + off]; int oi = mi[t + off];
      if (ov > mv[t] || (ov == mv[t] && oi < mi[t])) { mv[t] = ov; mi[t] = oi; }
    }
    __syncthreads();
  }
  if (t == 0) yhat[c] = (float)mi[0];
}

extern "C" void kernel_launch(void* const* d_in, const int* in_sizes, int n_in,
                              void* d_out, int out_size, void* d_ws, size_t ws_size,
                              hipStream_t stream) {
  (void)in_sizes; (void)n_in; (void)out_size; (void)ws_size;
  const float* x    = (const float*)d_in[0];
  const float* fc1w = (const float*)d_in[1];
  const float* fc1b = (const float*)d_in[2];
  const float* fc2w = (const float*)d_in[3];
  const float* fc2b = (const float*)d_in[4];
  const float* w1   = (const float*)d_in[5];
  const float* b1   = (const float*)d_in[6];
  const float* w2   = (const float*)d_in[7];
  const float* b2   = (const float*)d_in[8];
  const int*   comp = (const int*)d_in[9];

  char* ws = (char*)d_ws;
  const size_t MB = 1024ull * 1024ull;
  // region plan (peak 160MB):
  //   [0,32M)    xh     -> dead after GEMM1 -> w1Th
  //   [32M,64M)  w1mT   -> dead after GEMM1 -> part (fp16 2x16MB)
  //   [64M,96M)  out1h  -> dead after GEMM2 -> logits
  //   [96M,160M) out2h
  _Float16* xh     = (_Float16*)(ws + 0);
  _Float16* w1mT   = (_Float16*)(ws + 32 * MB);
  _Float16* out1h  = (_Float16*)(ws + 64 * MB);
  _Float16* out2h  = (_Float16*)(ws + 96 * MB);
  _Float16* w1Th   = (_Float16*)(ws + 0);
  _Float16* part   = (_Float16*)(ws + 32 * MB);
  float*    logits = (float*)(ws + 64 * MB);
  float*    outF   = (float*)d_out;

  hipFuncSetAttribute(reinterpret_cast<const void*>(k_gemm8<0>),
                      hipFuncAttributeMaxDynamicSharedMemorySize, 131072);
  hipFuncSetAttribute(reinterpret_cast<const void*>(k_gemm8<1>),
                      hipFuncAttributeMaxDynamicSharedMemorySize, 131072);

  // 1) pack x -> fp16
  k_pack_f16<<<(NB * NIN / 4) / 256, 256, 0, stream>>>(x, xh, NB * NIN / 4);
  // 2) pack (fc1_w * mask1)^T -> fp16 [P1][IN]
  k_packT<true><<<dim3(NP1 / 64, NIN / 64), 256, 0, stream>>>(fc1w, comp, w1mT, NIN, NP1);
  // 3) GEMM1: out1 = x @ fc1w_masked + fc1_b
  k_gemm8<0><<<(NB / 256) * (NP1 / 256), 512, 131072, stream>>>(
      xh, w1mT, fc1b, out1h, NB, NP1, NIN, NP1 / 256, 1);
  // 4) block-diagonal GEMM2 -> out2 fp16
  k_gemm2<<<(NB / 64) * (NNP / 32), 256, 0, stream>>>(out1h, fc2w, fc2b, out2h);
  // 5) pack w1^T -> fp16 [H][P2] (overlays dead xh)
  k_packT<false><<<dim3(NH / 64, NP2 / 64), 256, 0, stream>>>(w1, nullptr, w1Th, NP2, NH);
  // 6) GEMM3 split-K=2: fp16 partials = out2 @ w1 (overlays dead w1mT)
  k_gemm8<1><<<(NB / 256) * (NH / 256) * 2, 512, 131072, stream>>>(
      out2h, w1Th, nullptr, part, NB, NH, NP2, NH / 256, 2);
  // 7) fused: h = relu(p0+p1+b1); logits = h@w2+b2; hazards = sigmoid
  k_logits<<<NB / 4, 256, 0, stream>>>(part, b1, w2, b2, logits, outF);
  // 8) S and Y_hat
  k_final<<<4, 256, 0, stream>>>(logits, outF, outF + NB * 4, outF + 2 * NB * 4);
}

// Round 13
// 336.071 us; speedup vs baseline: 1.0031x; 1.0022x over previous
//
#include <hip/hip_runtime.h>
#include <cmath>

typedef _Float16 h8  __attribute__((ext_vector_type(8)));
typedef _Float16 h4v __attribute__((ext_vector_type(4)));
typedef float    f4  __attribute__((ext_vector_type(4)));

#define NB  4096
#define NIN 4096
#define NNP 512
#define NP1 4096
#define NP2 8192
#define NH  2048

__device__ __forceinline__ void g2l(const void* g, void* l) {
  __builtin_amdgcn_global_load_lds((const __attribute__((address_space(1))) void*)g,
                                   (__attribute__((address_space(3))) void*)l, 16, 0, 0);
}

// ---------------- pack f32 -> f16 (vectorized) ----------------
__global__ __launch_bounds__(256) void k_pack_f16(const float* __restrict__ in,
                                                  _Float16* __restrict__ out, int n4) {
  int i = blockIdx.x * 256 + threadIdx.x;
  if (i >= n4) return;
  f4 v = ((const f4*)in)[i];
  h4v o;
  o[0] = (_Float16)v[0]; o[1] = (_Float16)v[1];
  o[2] = (_Float16)v[2]; o[3] = (_Float16)v[3];
  ((h4v*)out)[i] = o;
}

// ---------------- transpose pack: out[n][k] = in[k][n] * optional mask ----------------
template<bool MASK>
__global__ __launch_bounds__(256) void k_packT(const float* __restrict__ in,
                                               const int* __restrict__ comp,
                                               _Float16* __restrict__ out, int K, int N) {
  __shared__ float tile[64][65];
  const int n0 = blockIdx.x * 64, k0 = blockIdx.y * 64;
  const int tx = threadIdx.x & 63, ty = threadIdx.x >> 6;
#pragma unroll
  for (int r = 0; r < 16; ++r) {
    int kk = r * 4 + ty;
    float v = in[(long)(k0 + kk) * N + n0 + tx];
    if (MASK) v *= (float)comp[(long)(k0 + kk) * NNP + ((n0 + tx) >> 3)];
    tile[kk][tx] = v;
  }
  __syncthreads();
#pragma unroll
  for (int r = 0; r < 16; ++r) {
    int nn = r * 4 + ty;
    out[(long)(n0 + nn) * K + k0 + tx] = (_Float16)tile[tx][nn];
  }
}

// ---------------- 256x256 fp16 GEMM, 16x16x32 frags, read-ahead pipelined 8-phase ----------------
// C = A[M,K] * BT[N,K]^T. EPI=0: C = acc + bias (fp16). EPI=1: fp16 split-K partial at ks*M*N.
// 8 waves (2m x 4n). A row = mh*128 + wm*64 + m*16 + lh ; B row = nh*128 + wn*32 + n*16 + lh.
// LDS 128KB: 2buf x {A half0,half1 ; B half0,half1}, each half [128 rows][128B] fp16.
// Zero-conflict read col (verified R6): (kq*64 + ls*16) ^ ((lh&7)<<4); staging = linear LDS
// dest + pre-swizzled global source.
// Pipelining: each phase's ds_reads load the NEXT phase's fragments into alternate register
// sets (afA/afB, bfA/bfB; B parity swaps per tile) -> MFMA never waits on LDS latency.
// Stages for tile t+2 spread P1..P4 of tile t; one vmcnt(6) per K-tile (ledger: 14 out, retires
// exactly the next tile's 8 stages). Plain ds_reads: compiler emits counted lgkm waits.
template<int EPI>
__global__ __launch_bounds__(512, 1) void k_gemm8(
    const _Float16* __restrict__ A, const _Float16* __restrict__ BT,
    const float* __restrict__ bias, _Float16* __restrict__ C,
    int M, int N, int K, int nbn, int ksplit) {
  extern __shared__ char smem[];
  // bijective XCD swizzle
  const int nwg = gridDim.x;
  const int q = nwg >> 3, r = nwg & 7;
  const int xcd = blockIdx.x & 7, idx = blockIdx.x >> 3;
  const int wg = (xcd < r ? xcd * (q + 1) : r * (q + 1) + (xcd - r) * q) + idx;
  const int tpk = nwg / ksplit;
  const int ks = wg / tpk;
  const int rem = wg - ks * tpk;
  const int bm = rem / nbn, bn = rem % nbn;
  const long m0 = (long)bm << 8, n0 = (long)bn << 8;
  const int Ks = K / ksplit;
  const int NT = Ks >> 6;              // BK=64, NT even (K multiples of 128)

  const int tid = threadIdx.x;
  const int lane = tid & 63, w = tid >> 6;
  const int wm = w >> 2, wn = w & 3;
  const int lh = lane & 15, ls = lane >> 4;
  const int swz = (lh & 7) << 4;
  const int c0 = (ls * 16) ^ swz;
  const int c1 = (64 + ls * 16) ^ swz;
  const int arow = (wm * 64 + lh) * 128;           // + mh*16384 + m_*2048
  const int brow = 32768 + (wn * 32 + lh) * 128;   // + nh*16384 + n_*2048

  const long sKb = (long)K * 2;
  const int scb = (((tid & 7) ^ ((tid >> 3) & 7)) << 4);
  const char* Ag = (const char*)A + (m0 + (tid >> 3)) * sKb + (long)ks * Ks * 2 + scb;
  const char* Bg = (const char*)BT + (n0 + (tid >> 3)) * sKb + (long)ks * Ks * 2 + scb;
  const long h64 = 64 * sKb, h128 = 128 * sKb;
  const int lw = w << 10;

#define STAGE_A(buf, hh, kb) do { \
    const char* s_ = Ag + (hh) * h128 + (kb); \
    char* d_ = smem + (buf) * 65536 + (hh) * 16384 + lw; \
    g2l(s_, d_); g2l(s_ + h64, d_ + 8192); } while (0)
#define STAGE_B(buf, hh, kb) do { \
    const char* s_ = Bg + (hh) * h128 + (kb); \
    char* d_ = smem + (buf) * 65536 + 32768 + (hh) * 16384 + lw; \
    g2l(s_, d_); g2l(s_ + h64, d_ + 8192); } while (0)
#define READ_A(dst, buf, mh) do { \
    _Pragma("unroll") for (int m_ = 0; m_ < 4; ++m_) { \
      dst[m_][0] = *(const h8*)(smem + (buf) * 65536 + (mh) * 16384 + arow + m_ * 2048 + c0); \
      dst[m_][1] = *(const h8*)(smem + (buf) * 65536 + (mh) * 16384 + arow + m_ * 2048 + c1); } } while (0)
#define READ_B(dst, buf, nh) do { \
    _Pragma("unroll") for (int n_ = 0; n_ < 2; ++n_) { \
      dst[n_][0] = *(const h8*)(smem + (buf) * 65536 + (nh) * 16384 + brow + n_ * 2048 + c0); \
      dst[n_][1] = *(const h8*)(smem + (buf) * 65536 + (nh) * 16384 + brow + n_ * 2048 + c1); } } while (0)
#define MM(mh, nh, aset, bset) do { \
    _Pragma("unroll") for (int kq_ = 0; kq_ < 2; ++kq_) \
    _Pragma("unroll") for (int m_ = 0; m_ < 4; ++m_) \
    _Pragma("unroll") for (int n_ = 0; n_ < 2; ++n_) \
      acc[mh][nh][m_][n_] = __builtin_amdgcn_mfma_f32_16x16x32_f16(aset[m_][kq_], bset[n_][kq_], acc[mh][nh][m_][n_], 0, 0, 0); } while (0)
#define BAR() asm volatile("s_barrier" ::: "memory")
#define VM6() asm volatile("s_waitcnt vmcnt(6)" ::: "memory")
#define VM8() asm volatile("s_waitcnt vmcnt(8)" ::: "memory")
#define PR1() __builtin_amdgcn_s_setprio(1)
#define PR0() __builtin_amdgcn_s_setprio(0)

  f4 acc[2][2][4][2] = {};   // [mh][nh][m][n]
  h8 afA[4][2], afB[4][2];   // A half0 / half1 fragment sets
  h8 bfA[2][2], bfB[2][2];   // B sets: even tiles B0->bfA,B1->bfB; odd tiles swapped

  auto kc = [&](int t) -> long { return (long)(t < NT ? t : NT - 1) << 7; };

  // prologue: stage tile0->buf0 (8 g2l), tile1->buf1 (8 g2l); retire tile0; preload A0,B0(t0)
  STAGE_A(0, 0, kc(0)); STAGE_B(0, 0, kc(0)); STAGE_B(0, 1, kc(0)); STAGE_A(0, 1, kc(0));
  STAGE_A(1, 0, kc(1)); STAGE_B(1, 0, kc(1)); STAGE_B(1, 1, kc(1)); STAGE_A(1, 1, kc(1));
  VM8();
  BAR();
  READ_A(afA, 0, 0);
  READ_B(bfA, 0, 0);

  for (int t2 = 0; t2 < NT; t2 += 2) {
    // ================= even tile t2 (buf0) =================
    // P1: MFMA(A0,B0); read B1(t2) ahead; stage A0(t2+2)
    BAR();
    READ_B(bfB, 0, 1);
    STAGE_A(0, 0, kc(t2 + 2));
    PR1(); MM(0, 0, afA, bfA); PR0();
    // P2: MFMA(A0,B1); read A1(t2) ahead; stage B1(t2+2)
    BAR();
    READ_A(afB, 0, 1);
    STAGE_B(0, 1, kc(t2 + 2));
    PR1(); MM(0, 1, afA, bfB); PR0();
    // P3: MFMA(A1,B1); gate tile t2+1 (vmcnt ledger = 14 -> retire its 8); read A0(t2+1)
    BAR();
    STAGE_A(0, 1, kc(t2 + 2));
    VM6();
    READ_A(afA, 1, 0);
    PR1(); MM(1, 1, afB, bfB); PR0();
    // P4: MFMA(A1,B0); read B0(t2+1)->bfB (odd parity); stage B0(t2+2)
    BAR();
    READ_B(bfB, 1, 0);
    STAGE_B(0, 0, kc(t2 + 2));
    PR1(); MM(1, 0, afB, bfA); PR0();
    // ================= odd tile t2+1 (buf1) =================
    // P5: MFMA(A0,B0=bfB); read B1(t2+1)->bfA; stage A0(t2+3)
    BAR();
    READ_B(bfA, 1, 1);
    STAGE_A(1, 0, kc(t2 + 3));
    PR1(); MM(0, 0, afA, bfB); PR0();
    // P6: MFMA(A0,B1=bfA); read A1(t2+1); stage B1(t2+3)
    BAR();
    READ_A(afB, 1, 1);
    STAGE_B(1, 1, kc(t2 + 3));
    PR1(); MM(0, 1, afA, bfA); PR0();
    // P7: MFMA(A1,B1=bfA); gate tile t2+2 (retire P1..P4 stages); read A0(t2+2)
    BAR();
    STAGE_A(1, 1, kc(t2 + 3));
    VM6();
    READ_A(afA, 0, 0);
    PR1(); MM(1, 1, afB, bfA); PR0();
    // P8: MFMA(A1,B0=bfB); read B0(t2+2)->bfA (even parity); stage B0(t2+3)
    BAR();
    READ_B(bfA, 0, 0);
    STAGE_B(1, 0, kc(t2 + 3));
    PR1(); MM(1, 0, afB, bfB); PR0();
  }

  // epilogue: 16x16 C/D layout col=lane&15, row=(lane>>4)*4+j
  _Float16* dst = (EPI == 1) ? (C + (long)ks * M * N) : C;
#pragma unroll
  for (int mh = 0; mh < 2; ++mh)
#pragma unroll
  for (int m = 0; m < 4; ++m) {
    const long r0 = m0 + mh * 128 + wm * 64 + m * 16 + ls * 4;
#pragma unroll
    for (int nh = 0; nh < 2; ++nh)
#pragma unroll
    for (int n = 0; n < 2; ++n) {
      const long c = n0 + nh * 128 + wn * 32 + n * 16 + lh;
      const float bv = (EPI == 0) ? bias[c] : 0.f;
#pragma unroll
      for (int j = 0; j < 4; ++j)
        dst[(r0 + j) * N + c] = (_Float16)(acc[mh][nh][m][n][j] + bv);
    }
  }
#undef STAGE_A
#undef STAGE_B
#undef READ_A
#undef READ_B
#undef MM
#undef BAR
#undef VM6
#undef VM8
#undef PR1
#undef PR0
}

// ---------------- block-diagonal GEMM2 ----------------
__global__ __launch_bounds__(256) void k_gemm2(const _Float16* __restrict__ out1,
                                               const float* __restrict__ fc2w,
                                               const float* __restrict__ fc2b,
                                               _Float16* __restrict__ out2) {
  const int b0 = (blockIdx.x >> 4) * 64;
  const int p  = (blockIdx.x & 15) * 32 + (threadIdx.x & 31);
  const int bsub = threadIdx.x >> 5;
  f4 bb0 = *(const f4*)&fc2b[p * 16 + 0];
  f4 bb1 = *(const f4*)&fc2b[p * 16 + 4];
  f4 bb2 = *(const f4*)&fc2b[p * 16 + 8];
  f4 bb3 = *(const f4*)&fc2b[p * 16 + 12];
  for (int r = 0; r < 8; ++r) {
    const int b = b0 + r * 8 + bsub;
    h8 qv = *(const h8*)&out1[(long)b * NP1 + p * 8];
    f4 a0 = bb0, a1 = bb1, a2 = bb2, a3 = bb3;
#pragma unroll
    for (int i = 0; i < 8; ++i) {
      const float qi = (float)qv[i];
      const f4* wr = (const f4*)&fc2w[(long)(p * 8 + i) * NP2 + p * 16];
      a0 += qi * wr[0]; a1 += qi * wr[1]; a2 += qi * wr[2]; a3 += qi * wr[3];
    }
    h8 o0, o1;
#pragma unroll
    for (int u = 0; u < 4; ++u) {
      o0[u] = (_Float16)a0[u]; o0[4 + u] = (_Float16)a1[u];
      o1[u] = (_Float16)a2[u]; o1[4 + u] = (_Float16)a3[u];
    }
    h8* dstp = (h8*)&out2[(long)b * NP2 + p * 16];
    dstp[0] = o0; dstp[1] = o1;
  }
}

// ---------------- fused splitK-reduce + bias + relu + GEMM4 + sigmoid ----------------
__global__ __launch_bounds__(256) void k_logits(const _Float16* __restrict__ part,
                                                const float* __restrict__ b1,
                                                const float* __restrict__ w2,
                                                const float* __restrict__ b2,
                                                float* __restrict__ logits,
                                                float* __restrict__ hazards) {
  const int lane = threadIdx.x & 63;
  const int b = blockIdx.x * 4 + (threadIdx.x >> 6);
  const long off2 = (long)NB * NH;
  f4 acc = {0.f, 0.f, 0.f, 0.f};
  const _Float16* p0 = part + (long)b * NH;
  const _Float16* p1 = p0 + off2;
#pragma unroll
  for (int c4 = 0; c4 < 4; ++c4) {
    const int k0 = c4 * 512 + lane * 8;
    h8 a = *(const h8*)&p0[k0];
    h8 bb = *(const h8*)&p1[k0];
    f4 bva = *(const f4*)&b1[k0];
    f4 bvb = *(const f4*)&b1[k0 + 4];
#pragma unroll
    for (int u = 0; u < 8; ++u) {
      const float bias = (u < 4) ? bva[u] : bvb[u - 4];
      const float hv = fmaxf((float)a[u] + (float)bb[u] + bias, 0.f);
      acc += hv * *(const f4*)&w2[(long)(k0 + u) * 4];
    }
  }
#pragma unroll
  for (int off = 32; off > 0; off >>= 1) {
#pragma unroll
    for (int u = 0; u < 4; ++u) acc[u] += __shfl_xor(acc[u], off, 64);
  }
  if (lane == 0) {
    f4 lg = acc + *(const f4*)b2;
    ((f4*)logits)[b] = lg;
    f4 hz;
#pragma unroll
    for (int u = 0; u < 4; ++u) hz[u] = 1.f / (1.f + expf(-lg[u]));
    ((f4*)hazards)[b] = hz;
  }
}

// ---------------- cumprod along batch + first-occurrence argmax ----------------
__global__ __launch_bounds__(256) void k_final(const float* __restrict__ logits,
                                               const float* __restrict__ hazards,
                                               float* __restrict__ S,
                                               float* __restrict__ yhat) {
  const int c = blockIdx.x;
  const int t = threadIdx.x;
  __shared__ float pl[256];
  __shared__ float mv[256];
  __shared__ int   mi[256];
  float prod = 1.f;
  float best = -1e30f; int bi = 0;
  for (int i = 0; i < 16; ++i) {
    const int b = t * 16 + i;
    prod *= (1.f - hazards[b * 4 + c]);
    const float lg = logits[b * 4 + c];
    if (lg > best) { best = lg; bi = b; }
  }
  pl[t] = prod; mv[t] = best; mi[t] = bi;
  __syncthreads();
  for (int off = 1; off < 256; off <<= 1) {
    float cur  = pl[t];
    float prev = (t >= off) ? pl[t - off] : 1.f;
    __syncthreads();
    pl[t] = cur * prev;
    __syncthreads();
  }
  float s = (t == 0) ? 1.f : pl[t - 1];
  for (int i = 0; i < 16; ++i) {
    const int b = t * 16 + i;
    s *= (1.f - hazards[b * 4 + c]);
    S[b * 4 + c] = s;
  }
  for (int off = 128; off > 0; off >>= 1) {
    if (t < off) {
      float ov = mv[t + off]; int oi = mi[t + off];
      if (ov > mv[t] || (ov == mv[t] && oi < mi[t])) { mv[t] = ov; mi[t] = oi; }
    }
    __syncthreads();
  }
  if (t == 0) yhat[c] = (float)mi[0];
}

extern "C" void kernel_launch(void* const* d_in, const int* in_sizes, int n_in,
                              void* d_out, int out_size, void* d_ws, size_t ws_size,
                              hipStream_t stream) {
  (void)in_sizes; (void)n_in; (void)out_size; (void)ws_size;
  const float* x    = (const float*)d_in[0];
  const float* fc1w = (const float*)d_in[1];
  const float* fc1b = (const float*)d_in[2];
  const float* fc2w = (const float*)d_in[3];
  const float* fc2b = (const float*)d_in[4];
  const float* w1   = (const float*)d_in[5];
  const float* b1   = (const float*)d_in[6];
  const float* w2   = (const float*)d_in[7];
  const float* b2   = (const float*)d_in[8];
  const int*   comp = (const int*)d_in[9];

  char* ws = (char*)d_ws;
  const size_t MB = 1024ull * 1024ull;
  // region plan (peak 160MB):
  //   [0,32M)    xh     -> dead after GEMM1 -> w1Th
  //   [32M,64M)  w1mT   -> dead after GEMM1 -> part (fp16 2x16MB)
  //   [64M,96M)  out1h  -> dead after GEMM2 -> logits
  //   [96M,160M) out2h
  _Float16* xh     = (_Float16*)(ws + 0);
  _Float16* w1mT   = (_Float16*)(ws + 32 * MB);
  _Float16* out1h  = (_Float16*)(ws + 64 * MB);
  _Float16* out2h  = (_Float16*)(ws + 96 * MB);
  _Float16* w1Th   = (_Float16*)(ws + 0);
  _Float16* part   = (_Float16*)(ws + 32 * MB);
  float*    logits = (float*)(ws + 64 * MB);
  float*    outF   = (float*)d_out;

  hipFuncSetAttribute(reinterpret_cast<const void*>(k_gemm8<0>),
                      hipFuncAttributeMaxDynamicSharedMemorySize, 131072);
  hipFuncSetAttribute(reinterpret_cast<const void*>(k_gemm8<1>),
                      hipFuncAttributeMaxDynamicSharedMemorySize, 131072);

  // 1) pack x -> fp16
  k_pack_f16<<<(NB * NIN / 4) / 256, 256, 0, stream>>>(x, xh, NB * NIN / 4);
  // 2) pack (fc1_w * mask1)^T -> fp16 [P1][IN]
  k_packT<true><<<dim3(NP1 / 64, NIN / 64), 256, 0, stream>>>(fc1w, comp, w1mT, NIN, NP1);
  // 3) GEMM1: out1 = x @ fc1w_masked + fc1_b
  k_gemm8<0><<<(NB / 256) * (NP1 / 256), 512, 131072, stream>>>(
      xh, w1mT, fc1b, out1h, NB, NP1, NIN, NP1 / 256, 1);
  // 4) block-diagonal GEMM2 -> out2 fp16
  k_gemm2<<<(NB / 64) * (NNP / 32), 256, 0, stream>>>(out1h, fc2w, fc2b, out2h);
  // 5) pack w1^T -> fp16 [H][P2] (overlays dead xh)
  k_packT<false><<<dim3(NH / 64, NP2 / 64), 256, 0, stream>>>(w1, nullptr, w1Th, NP2, NH);
  // 6) GEMM3 split-K=2: fp16 partials = out2 @ w1 (overlays dead w1mT)
  k_gemm8<1><<<(NB / 256) * (NH / 256) * 2, 512, 131072, stream>>>(
      out2h, w1Th, nullptr, part, NB, NH, NP2, NH / 256, 2);
  // 7) fused: h = relu(p0+p1+b1); logits = h@w2+b2; hazards = sigmoid
  k_logits<<<NB / 4, 256, 0, stream>>>(part, b1, w2, b2, logits, outF);
  // 8) S and Y_hat
  k_final<<<4, 256, 0, stream>>>(logits, outF, outF + NB * 4, outF + 2 * NB * 4);
}